// Round 15
// baseline (236.832 us; speedup 1.0000x reference)
//
#include <hip/hip_runtime.h>
#include <hip/hip_fp16.h>

#define N_NODES 50000
#define N_EDGES 800000
#define IN_DIM 128
#define HID 64
#define NUM_GRAPHS 64
#define NB 196        // buckets: dst >> 8 (256 node-ids per bucket)
#define NBLK 64       // blocks in hist/bin passes (edge->block map must match)

__device__ inline float4 load_h4(const __half* p) {
    const __half2* q = (const __half2*)p;
    float2 a = __half22float2(q[0]);
    float2 b = __half22float2(q[1]);
    return make_float4(a.x, a.y, b.x, b.y);
}
__device__ inline void store_h4(__half* p, float4 v) {
    __half2* q = (__half2*)p;
    q[0] = __floats2half2_rn(v.x, v.y);
    q[1] = __floats2half2_rn(v.z, v.w);
}
// 16B load of 8 halves -> 8 floats
__device__ inline void load_h8(const __half* p, float* f) {
    float4 r = *(const float4*)p;
    const __half2* h = (const __half2*)&r;
    float2 a0 = __half22float2(h[0]);
    float2 a1 = __half22float2(h[1]);
    float2 a2 = __half22float2(h[2]);
    float2 a3 = __half22float2(h[3]);
    f[0] = a0.x; f[1] = a0.y; f[2] = a1.x; f[3] = a1.y;
    f[4] = a2.x; f[5] = a2.y; f[6] = a3.x; f[7] = a3.y;
}
__device__ inline void store_h8(__half* p, const float* f) {
    __half2 hs[4];
    hs[0] = __floats2half2_rn(f[0], f[1]);
    hs[1] = __floats2half2_rn(f[2], f[3]);
    hs[2] = __floats2half2_rn(f[4], f[5]);
    hs[3] = __floats2half2_rn(f[6], f[7]);
    *(float4*)p = *(const float4*)hs;
}

// Shared GEMM body. Output SPLIT into two [nRows][32] fp16 half-tables (out_lo cols
// 0-31, out_hi cols 32-63) so the agg gather's working set per pass is a contiguous
// 3.2MB table that FITS one XCD's 4MB L2 (round-13: monolithic 6.4MB table thrashed:
// 9% HBM, FETCH 32MB). IN_SPLIT: input is split fp16 half-tables (gemm2); else fp32 [N][K].
template <int K, bool IN_SPLIT, bool SCALE>
__device__ __forceinline__ void gemm_body(const float* __restrict__ Af,
                                          const __half* __restrict__ Alo, const __half* __restrict__ Ahi,
                                          const float* __restrict__ W, const float* __restrict__ dinv,
                                          __half* __restrict__ out_lo, __half* __restrict__ out_hi,
                                          int nRows, int node0, float* xs, float* ws) {
    int tid = threadIdx.x;
    int c0 = (tid & 15) * 4, n0 = (tid >> 4) * 4;
    float acc[4][4] = {};
    for (int kb = 0; kb < K; kb += 64) {
        for (int i = tid; i < 64 * 16; i += 256) {
            int k = i >> 4, c4 = (i & 15) * 4;
            *(float4*)&ws[k * 68 + c4] = *(const float4*)&W[(size_t)(kb + k) * 64 + c4];
        }
        for (int i = tid; i < 64 * 16; i += 256) {
            int n = i >> 4, k4 = (i & 15) * 4;
            int gn = node0 + n;
            float4 v;
            if (gn < nRows) {
                if constexpr (!IN_SPLIT) {
                    v = *(const float4*)&Af[(size_t)gn * K + kb + k4];
                } else {
                    int k = kb + k4;   // K==64: kb==0
                    v = (k < 32) ? load_h4(&Alo[(size_t)gn * 32 + k])
                                 : load_h4(&Ahi[(size_t)gn * 32 + (k - 32)]);
                }
            } else v = make_float4(0.f, 0.f, 0.f, 0.f);
            *(float4*)&xs[n * 68 + k4] = v;
        }
        __syncthreads();
        for (int k = 0; k < 64; k += 4) {
            float4 x0 = *(const float4*)&xs[(n0 + 0) * 68 + k];
            float4 x1 = *(const float4*)&xs[(n0 + 1) * 68 + k];
            float4 x2 = *(const float4*)&xs[(n0 + 2) * 68 + k];
            float4 x3 = *(const float4*)&xs[(n0 + 3) * 68 + k];
            #define KSTEP(KK, F) { \
                float4 wr = *(const float4*)&ws[(k + KK) * 68 + c0]; \
                acc[0][0] += x0.F * wr.x; acc[0][1] += x0.F * wr.y; acc[0][2] += x0.F * wr.z; acc[0][3] += x0.F * wr.w; \
                acc[1][0] += x1.F * wr.x; acc[1][1] += x1.F * wr.y; acc[1][2] += x1.F * wr.z; acc[1][3] += x1.F * wr.w; \
                acc[2][0] += x2.F * wr.x; acc[2][1] += x2.F * wr.y; acc[2][2] += x2.F * wr.z; acc[2][3] += x2.F * wr.w; \
                acc[3][0] += x3.F * wr.x; acc[3][1] += x3.F * wr.y; acc[3][2] += x3.F * wr.z; acc[3][3] += x3.F * wr.w; }
            KSTEP(0, x)
            KSTEP(1, y)
            KSTEP(2, z)
            KSTEP(3, w)
            #undef KSTEP
        }
        __syncthreads();
    }
    #pragma unroll
    for (int i = 0; i < 4; i++) {
        int gn = node0 + n0 + i;
        if (gn < nRows) {
            float sc = 1.0f;
            if constexpr (SCALE) sc = dinv[gn];
            float4 r = make_float4(acc[i][0] * sc, acc[i][1] * sc, acc[i][2] * sc, acc[i][3] * sc);
            if (c0 < 32) store_h4(&out_lo[(size_t)gn * 32 + c0], r);
            else         store_h4(&out_hi[(size_t)gn * 32 + (c0 - 32)], r);
        }
    }
}

// K1: block-partitioned fusion. [round-8 proven: LDS histogram, NOT global atomics —
// round-11 measured device-scope atomicAdd as memory-side RMW: WRITE_SIZE 6.4->31MB]
//   blocks [0, NBLK)  : dst histogram over NB buckets (bucket-major hist_g)
//   blocks [NBLK, ..) : gemm1 = x @ W1 -> fp16 h1_lo/h1_hi (UNSCALED; dinv in agg1)
__global__ __launch_bounds__(256) void k1_kernel(const int* __restrict__ dst, int* __restrict__ hist_g,
                                                 const float* __restrict__ x, const float* __restrict__ W1,
                                                 __half* __restrict__ h1_lo, __half* __restrict__ h1_hi) {
    __shared__ __align__(16) float smem[2 * 64 * 68];   // 34816 B, aliased per role
    int blk = blockIdx.x, tid = threadIdx.x;
    if (blk < NBLK) {
        int* h = (int*)smem;
        for (int i = tid; i < NB; i += 256) h[i] = 0;
        __syncthreads();
        const int NI = N_EDGES / 4;
        for (int i = blk * 256 + tid; i < NI; i += NBLK * 256) {
            int4 d = ((const int4*)dst)[i];
            atomicAdd(&h[d.x >> 8], 1);
            atomicAdd(&h[d.y >> 8], 1);
            atomicAdd(&h[d.z >> 8], 1);
            atomicAdd(&h[d.w >> 8], 1);
        }
        __syncthreads();
        for (int i = tid; i < NB; i += 256) hist_g[i * NBLK + blk] = h[i];
    } else {
        int node0 = (blk - NBLK) * 64;
        gemm_body<IN_DIM, false, false>(x, nullptr, nullptr, W1, nullptr, h1_lo, h1_hi,
                                        N_NODES, node0, smem, smem + 64 * 68);
    }
}

// K2: fused scan+bin. Each block loads hist_g (12544 ints) into LDS, exclusive-scans it
// locally (replicated across blocks on idle CUs), takes its own cursor column, and bins
// edges bucket-major, packed 4B: src(16b) | (dst&255)<<16. Block 0 also emits bucket bases.
__global__ __launch_bounds__(256) void k2_binscan(const int* __restrict__ hist_g,
                                                  const int* __restrict__ src, const int* __restrict__ dst,
                                                  int* __restrict__ binned, int* __restrict__ bstart,
                                                  int* __restrict__ offs) {
    __shared__ int ld[NB * NBLK];   // 12544 ints = 50176 B
    __shared__ int cur[NB];
    __shared__ int wsum[4];
    int tid = threadIdx.x, blk = blockIdx.x;
    for (int i = tid; i < NB * NBLK; i += 256) ld[i] = hist_g[i];
    __syncthreads();
    const int CH = (NB * NBLK) / 256;   // 49
    int base = tid * CH;
    int s = 0;
    for (int k = 0; k < CH; k++) { int v = ld[base + k]; ld[base + k] = s; s += v; }
    int lane = tid & 63, wid = tid >> 6;
    int inc = s;
    #pragma unroll
    for (int d = 1; d < 64; d <<= 1) { int t = __shfl_up(inc, d, 64); if (lane >= d) inc += t; }
    if (lane == 63) wsum[wid] = inc;
    __syncthreads();
    if (tid == 0) {
        int a = 0;
        for (int w = 0; w < 4; w++) { int t = wsum[w]; wsum[w] = a; a += t; }
    }
    __syncthreads();
    int off = wsum[wid] + inc - s;
    for (int k = 0; k < CH; k++) ld[base + k] += off;
    __syncthreads();
    for (int b = tid; b < NB; b += 256) cur[b] = ld[b * NBLK + blk];
    if (blk == 0) {
        for (int b = tid; b < NB; b += 256) bstart[b] = ld[b * NBLK];
        if (tid == 0) { bstart[NB] = N_EDGES; offs[N_NODES] = N_EDGES; }
    }
    __syncthreads();
    const int NI = N_EDGES / 4;
    for (int i = blk * 256 + tid; i < NI; i += NBLK * 256) {
        int4 sv = ((const int4*)src)[i];
        int4 dv = ((const int4*)dst)[i];
        int p0 = atomicAdd(&cur[dv.x >> 8], 1); binned[p0] = (sv.x & 0xFFFF) | ((dv.x & 255) << 16);
        int p1 = atomicAdd(&cur[dv.y >> 8], 1); binned[p1] = (sv.y & 0xFFFF) | ((dv.y & 255) << 16);
        int p2 = atomicAdd(&cur[dv.z >> 8], 1); binned[p2] = (sv.z & 0xFFFF) | ((dv.z & 255) << 16);
        int p3 = atomicAdd(&cur[dv.w >> 8], 1); binned[p3] = (sv.w & 0xFFFF) | ((dv.w & 255) << 16);
    }
}

// K3: one block per bucket — LDS counting sort by local id; writes offs, dinv, csr_src (u16).
__global__ __launch_bounds__(256) void build_kernel(const int* __restrict__ binned, const int* __restrict__ bstart,
                                                    int* __restrict__ offs, float* __restrict__ dinv,
                                                    unsigned short* __restrict__ csr_src) {
    __shared__ int cnt[256];
    __shared__ int excl[256];
    __shared__ int rnk[256];
    __shared__ int wtot[4];
    int b = blockIdx.x, tid = threadIdx.x;
    int base = bstart[b];
    int end  = bstart[b + 1];
    cnt[tid] = 0; rnk[tid] = 0;
    __syncthreads();
    for (int j = base + tid; j < end; j += 256) atomicAdd(&cnt[(binned[j] >> 16) & 255], 1);
    __syncthreads();
    int v = cnt[tid];
    int lane = tid & 63, wid = tid >> 6;
    int inc = v;
    #pragma unroll
    for (int d = 1; d < 64; d <<= 1) { int t = __shfl_up(inc, d, 64); if (lane >= d) inc += t; }
    if (lane == 63) wtot[wid] = inc;
    __syncthreads();
    if (tid == 0) {
        int a = 0;
        for (int w = 0; w < 4; w++) { int t = wtot[w]; wtot[w] = a; a += t; }
    }
    __syncthreads();
    excl[tid] = wtot[wid] + inc - v;
    int node = b * 256 + tid;
    if (node < N_NODES) {
        offs[node] = base + excl[tid];
        dinv[node] = rsqrtf((float)v + 1.0f);
    }
    __syncthreads();
    for (int j = base + tid; j < end; j += 256) {
        int e = binned[j];
        int l = (e >> 16) & 255;
        int r = atomicAdd(&rnk[l], 1);
        csr_src[base + excl[l] + r] = (unsigned short)(e & 0xFFFF);
    }
}

// K4a/K4b: layer-1 agg over a 32-col HALF table (3.2MB — L2-resident per XCD).
// out32[n,c] = relu( dinv[n]*Sum_{e:dst=n} hd32[src,c]*dinv[src] + dinv[n]^2*hd32[n,c] + b32[c] )
// Wave = 1 node; 16 groups x 4 lanes; group walks j=beg+grp step 16, 16B row loads (64B rows).
__global__ __launch_bounds__(256) void agg1h_kernel(const __half* __restrict__ hd32, const int* __restrict__ offs,
                                                    const unsigned short* __restrict__ csr_src,
                                                    const float* __restrict__ dinv, const float* __restrict__ bias32,
                                                    __half* __restrict__ out32) {
    int lane = threadIdx.x & 63;
    int node = blockIdx.x * 4 + (threadIdx.x >> 6);   // grid*4 == N_NODES exactly
    int grp = lane >> 2;
    int cc = (lane & 3) * 8;
    float acc[8] = {};
    int beg = offs[node], end = offs[node + 1];
    #pragma unroll 2
    for (int j = beg + grp; j < end; j += 16) {
        int s = csr_src[j];
        float dv = dinv[s];
        float hv[8];
        load_h8(&hd32[(size_t)s * 32 + cc], hv);
        #pragma unroll
        for (int i = 0; i < 8; i++) acc[i] = fmaf(hv[i], dv, acc[i]);
    }
    #pragma unroll
    for (int m = 4; m <= 32; m <<= 1) {
        #pragma unroll
        for (int i = 0; i < 8; i++) acc[i] += __shfl_xor(acc[i], m, 64);
    }
    if (grp == 0) {
        float di = dinv[node];
        float d2 = di * di;
        float hn[8];
        load_h8(&hd32[(size_t)node * 32 + cc], hn);
        float4 bv0 = *(const float4*)&bias32[cc];
        float4 bv1 = *(const float4*)&bias32[cc + 4];
        float bb[8] = {bv0.x, bv0.y, bv0.z, bv0.w, bv1.x, bv1.y, bv1.z, bv1.w};
        float r[8];
        #pragma unroll
        for (int i = 0; i < 8; i++) r[i] = fmaxf(fmaf(di, acc[i], fmaf(d2, hn[i], bb[i])), 0.0f);
        store_h8(&out32[(size_t)node * 32 + cc], r);
    }
}

// K5: gemm2 = (act @ W2) * dinv -> split fp16 h2_lo/h2_hi. Input act is split.
// [round-13: fusing gemm2 into agg1 as a shfl-matvec REGRESSED +14us. Keep split.]
__global__ __launch_bounds__(256) void gemm2_kernel(const __half* __restrict__ Alo, const __half* __restrict__ Ahi,
                                                    const float* __restrict__ W, const float* __restrict__ dinv,
                                                    __half* __restrict__ out_lo, __half* __restrict__ out_hi) {
    __shared__ __align__(16) float smem[2 * 64 * 68];
    gemm_body<HID, true, true>(nullptr, Alo, Ahi, W, dinv, out_lo, out_hi,
                               N_NODES, blockIdx.x * 64, smem, smem + 64 * 68);
}

// K6a/K6b: layer-2 agg over a 32-col half table + partial Wlin dot -> nd[node].
// Partials from the two halves are summed in graphred. No cross-block protocol
// (round-3: arrive atomics cost 265us).
__global__ __launch_bounds__(256) void agg2h_kernel(const __half* __restrict__ hd32, const int* __restrict__ offs,
                                                    const unsigned short* __restrict__ csr_src,
                                                    const float* __restrict__ dinv, const float* __restrict__ bias32,
                                                    const float* __restrict__ wlin32,
                                                    float* __restrict__ nd) {
    int lane = threadIdx.x & 63;
    int node = blockIdx.x * 4 + (threadIdx.x >> 6);   // grid*4 == N_NODES exactly
    int grp = lane >> 2;
    int cc = (lane & 3) * 8;
    float acc[8] = {};
    int beg = offs[node], end = offs[node + 1];
    #pragma unroll 2
    for (int j = beg + grp; j < end; j += 16) {
        int s = csr_src[j];
        float hv[8];
        load_h8(&hd32[(size_t)s * 32 + cc], hv);
        #pragma unroll
        for (int i = 0; i < 8; i++) acc[i] += hv[i];
    }
    #pragma unroll
    for (int m = 4; m <= 32; m <<= 1) {
        #pragma unroll
        for (int i = 0; i < 8; i++) acc[i] += __shfl_xor(acc[i], m, 64);
    }
    if (grp == 0) {
        float di = dinv[node];
        float hn[8];
        load_h8(&hd32[(size_t)node * 32 + cc], hn);
        float4 bv0 = *(const float4*)&bias32[cc];
        float4 bv1 = *(const float4*)&bias32[cc + 4];
        float bb[8] = {bv0.x, bv0.y, bv0.z, bv0.w, bv1.x, bv1.y, bv1.z, bv1.w};
        float4 wl0 = *(const float4*)&wlin32[cc];
        float4 wl1 = *(const float4*)&wlin32[cc + 4];
        float ww[8] = {wl0.x, wl0.y, wl0.z, wl0.w, wl1.x, wl1.y, wl1.z, wl1.w};
        float d = 0.0f;
        #pragma unroll
        for (int i = 0; i < 8; i++) {
            float rr = fmaxf(fmaf(di, acc[i] + hn[i], bb[i]), 0.0f);
            d = fmaf(rr, ww[i], d);
        }
        d += __shfl_xor(d, 1, 64);
        d += __shfl_xor(d, 2, 64);
        if ((lane & 3) == 0) nd[node] = d;
    }
}

// K7: batch is SORTED: block g binary-searches its node range and mean-reduces
// ndotA+ndotB into out[g]. One dispatch, no partials, no global atomics.
__global__ __launch_bounds__(256) void graphred_kernel(const float* __restrict__ ndA, const float* __restrict__ ndB,
                                                       const int* __restrict__ batch,
                                                       const float* __restrict__ blin, float* __restrict__ out) {
    __shared__ float wpart[4];
    int g = blockIdx.x;
    int tid = threadIdx.x;
    int lo = 0, hi = N_NODES;
    while (lo < hi) { int m = (lo + hi) >> 1; if (batch[m] < g) lo = m + 1; else hi = m; }
    int lo2 = lo, hi2 = N_NODES;
    while (lo2 < hi2) { int m = (lo2 + hi2) >> 1; if (batch[m] < g + 1) lo2 = m + 1; else hi2 = m; }
    float s = 0.0f;
    for (int i = lo + tid; i < lo2; i += 256) s += ndA[i] + ndB[i];
    int lane = tid & 63, wid = tid >> 6;
    #pragma unroll
    for (int m = 32; m > 0; m >>= 1) s += __shfl_down(s, m, 64);
    if (lane == 0) wpart[wid] = s;
    __syncthreads();
    if (tid == 0) {
        float t = wpart[0] + wpart[1] + wpart[2] + wpart[3];
        float cnt = (float)(lo2 - lo);
        out[g] = t / fmaxf(cnt, 1.0f) + blin[0];
    }
}

extern "C" void kernel_launch(void* const* d_in, const int* in_sizes, int n_in,
                              void* d_out, int out_size, void* d_ws, size_t ws_size,
                              hipStream_t stream) {
    const float* x    = (const float*)d_in[0];
    const int*   ei   = (const int*)d_in[1];
    const int*   batch= (const int*)d_in[2];
    const float* W1   = (const float*)d_in[3];
    const float* b1   = (const float*)d_in[4];
    const float* W2   = (const float*)d_in[5];
    const float* b2   = (const float*)d_in[6];
    const float* Wlin = (const float*)d_in[7];
    const float* blin = (const float*)d_in[8];
    float* out = (float*)d_out;
    const int* srcA = ei;
    const int* dstA = ei + N_EDGES;

    char* p = (char*)d_ws;
    auto alloc = [&](size_t n) { char* r = p; p += (n + 255) & ~(size_t)255; return r; };
    int*    hist_g  = (int*)alloc((size_t)NB * NBLK * 4);
    int*    bstart  = (int*)alloc((size_t)(NB + 1) * 4);
    int*    offs    = (int*)alloc((size_t)(N_NODES + 1) * 4);
    int*    binned  = (int*)alloc((size_t)N_EDGES * 4);
    unsigned short* csr_src = (unsigned short*)alloc((size_t)N_EDGES * 2);
    float*  dinv    = (float*)alloc((size_t)N_NODES * 4);
    float*  ndotA   = (float*)alloc((size_t)N_NODES * 4);
    float*  ndotB   = (float*)alloc((size_t)N_NODES * 4);
    __half* h1_lo   = (__half*)alloc((size_t)N_NODES * 32 * 2);
    __half* h1_hi   = (__half*)alloc((size_t)N_NODES * 32 * 2);
    __half* act_lo  = (__half*)alloc((size_t)N_NODES * 32 * 2);
    __half* act_hi  = (__half*)alloc((size_t)N_NODES * 32 * 2);
    __half* h2_lo   = (__half*)alloc((size_t)N_NODES * 32 * 2);
    __half* h2_hi   = (__half*)alloc((size_t)N_NODES * 32 * 2);
    // no memset needed: every buffer is fully written before read

    const int GEMM1_BLOCKS = (N_NODES + 63) / 64;               // 782
    k1_kernel<<<NBLK + GEMM1_BLOCKS, 256, 0, stream>>>(dstA, hist_g, x, W1, h1_lo, h1_hi);
    k2_binscan<<<NBLK, 256, 0, stream>>>(hist_g, srcA, dstA, binned, bstart, offs);
    build_kernel<<<NB, 256, 0, stream>>>(binned, bstart, offs, dinv, csr_src);
    agg1h_kernel<<<N_NODES / 4, 256, 0, stream>>>(h1_lo, offs, csr_src, dinv, b1,      act_lo);
    agg1h_kernel<<<N_NODES / 4, 256, 0, stream>>>(h1_hi, offs, csr_src, dinv, b1 + 32, act_hi);
    gemm2_kernel<<<GEMM1_BLOCKS, 256, 0, stream>>>(act_lo, act_hi, W2, dinv, h2_lo, h2_hi);
    agg2h_kernel<<<N_NODES / 4, 256, 0, stream>>>(h2_lo, offs, csr_src, dinv, b2,      Wlin,      ndotA);
    agg2h_kernel<<<N_NODES / 4, 256, 0, stream>>>(h2_hi, offs, csr_src, dinv, b2 + 32, Wlin + 32, ndotB);
    graphred_kernel<<<NUM_GRAPHS, 256, 0, stream>>>(ndotA, ndotB, batch, blin, out);
}

// Round 16
// 196.315 us; speedup vs baseline: 1.2064x; 1.2064x over previous
//
#include <hip/hip_runtime.h>
#include <hip/hip_fp16.h>

#define N_NODES 50000
#define N_EDGES 800000
#define IN_DIM 128
#define HID 64
#define NUM_GRAPHS 64
#define NB 196        // buckets: dst >> 8 (256 node-ids per bucket)
#define NBLK 64       // blocks in hist/bin passes (edge->block map must match)

__device__ inline float4 load_h4(const __half* p) {
    const __half2* q = (const __half2*)p;
    float2 a = __half22float2(q[0]);
    float2 b = __half22float2(q[1]);
    return make_float4(a.x, a.y, b.x, b.y);
}
__device__ inline void store_h4(__half* p, float4 v) {
    __half2* q = (__half2*)p;
    q[0] = __floats2half2_rn(v.x, v.y);
    q[1] = __floats2half2_rn(v.z, v.w);
}
// 16B load of 8 halves -> 8 floats
__device__ inline void load_h8(const __half* p, float* f) {
    float4 r = *(const float4*)p;
    const __half2* h = (const __half2*)&r;
    float2 a0 = __half22float2(h[0]);
    float2 a1 = __half22float2(h[1]);
    float2 a2 = __half22float2(h[2]);
    float2 a3 = __half22float2(h[3]);
    f[0] = a0.x; f[1] = a0.y; f[2] = a1.x; f[3] = a1.y;
    f[4] = a2.x; f[5] = a2.y; f[6] = a3.x; f[7] = a3.y;
}
__device__ inline void store_h8(__half* p, const float* f) {
    __half2 hs[4];
    hs[0] = __floats2half2_rn(f[0], f[1]);
    hs[1] = __floats2half2_rn(f[2], f[3]);
    hs[2] = __floats2half2_rn(f[4], f[5]);
    hs[3] = __floats2half2_rn(f[6], f[7]);
    *(float4*)p = *(const float4*)hs;
}

// Shared GEMM body: C = (A[nRows,K] @ W[K,64]) * (SCALE ? dinv[n] : 1) -> fp16.
// Block tile: 64 nodes x 64 cols; thread = 4 nodes x 4 contiguous cols. [proven shape]
// NOTE [round-15]: output stays MONOLITHIC [N][64] fp16 — 128B rows = exactly one
// cache line per gather, 100% line utilization. Split [N][32] halves measured +40us
// (64B rows waste half of every randomly-touched 128B line, 2x passes 2x line traffic).
template <int K, typename TIN, bool SCALE>
__device__ __forceinline__ void gemm_body(const TIN* __restrict__ A, const float* __restrict__ W,
                                          const float* __restrict__ dinv, __half* __restrict__ out,
                                          int nRows, int node0, float* xs, float* ws) {
    int tid = threadIdx.x;
    int c0 = (tid & 15) * 4, n0 = (tid >> 4) * 4;
    float acc[4][4] = {};
    for (int kb = 0; kb < K; kb += 64) {
        for (int i = tid; i < 64 * 16; i += 256) {
            int k = i >> 4, c4 = (i & 15) * 4;
            *(float4*)&ws[k * 68 + c4] = *(const float4*)&W[(size_t)(kb + k) * 64 + c4];
        }
        for (int i = tid; i < 64 * 16; i += 256) {
            int n = i >> 4, k4 = (i & 15) * 4;
            int gn = node0 + n;
            float4 v;
            if (gn < nRows) {
                if constexpr (sizeof(TIN) == 4) v = *(const float4*)&A[(size_t)gn * K + kb + k4];
                else                            v = load_h4((const __half*)&A[(size_t)gn * K + kb + k4]);
            } else v = make_float4(0.f, 0.f, 0.f, 0.f);
            *(float4*)&xs[n * 68 + k4] = v;
        }
        __syncthreads();
        for (int k = 0; k < 64; k += 4) {
            float4 x0 = *(const float4*)&xs[(n0 + 0) * 68 + k];
            float4 x1 = *(const float4*)&xs[(n0 + 1) * 68 + k];
            float4 x2 = *(const float4*)&xs[(n0 + 2) * 68 + k];
            float4 x3 = *(const float4*)&xs[(n0 + 3) * 68 + k];
            #define KSTEP(KK, F) { \
                float4 wr = *(const float4*)&ws[(k + KK) * 68 + c0]; \
                acc[0][0] += x0.F * wr.x; acc[0][1] += x0.F * wr.y; acc[0][2] += x0.F * wr.z; acc[0][3] += x0.F * wr.w; \
                acc[1][0] += x1.F * wr.x; acc[1][1] += x1.F * wr.y; acc[1][2] += x1.F * wr.z; acc[1][3] += x1.F * wr.w; \
                acc[2][0] += x2.F * wr.x; acc[2][1] += x2.F * wr.y; acc[2][2] += x2.F * wr.z; acc[2][3] += x2.F * wr.w; \
                acc[3][0] += x3.F * wr.x; acc[3][1] += x3.F * wr.y; acc[3][2] += x3.F * wr.z; acc[3][3] += x3.F * wr.w; }
            KSTEP(0, x)
            KSTEP(1, y)
            KSTEP(2, z)
            KSTEP(3, w)
            #undef KSTEP
        }
        __syncthreads();
    }
    #pragma unroll
    for (int i = 0; i < 4; i++) {
        int gn = node0 + n0 + i;
        if (gn < nRows) {
            float sc = 1.0f;
            if constexpr (SCALE) sc = dinv[gn];
            store_h4(&out[(size_t)gn * 64 + c0],
                     make_float4(acc[i][0] * sc, acc[i][1] * sc, acc[i][2] * sc, acc[i][3] * sc));
        }
    }
}

// K1: block-partitioned fusion. [round-8 proven: LDS histogram, NOT global atomics —
// round-11 measured device-scope atomicAdd as memory-side RMW: k1 WRITE_SIZE 6.4->31MB, +50us total]
//   blocks [0, NBLK)  : dst histogram over NB buckets (bucket-major hist_g)
//   blocks [NBLK, ..) : gemm1 = x @ W1 -> fp16 h1 (UNSCALED; dinv applied in agg1)
__global__ __launch_bounds__(256) void k1_kernel(const int* __restrict__ dst, int* __restrict__ hist_g,
                                                 const float* __restrict__ x, const float* __restrict__ W1,
                                                 __half* __restrict__ h1) {
    __shared__ __align__(16) float smem[2 * 64 * 68];   // 34816 B, aliased per role
    int blk = blockIdx.x, tid = threadIdx.x;
    if (blk < NBLK) {
        int* h = (int*)smem;
        for (int i = tid; i < NB; i += 256) h[i] = 0;
        __syncthreads();
        const int NI = N_EDGES / 4;
        for (int i = blk * 256 + tid; i < NI; i += NBLK * 256) {
            int4 d = ((const int4*)dst)[i];
            atomicAdd(&h[d.x >> 8], 1);
            atomicAdd(&h[d.y >> 8], 1);
            atomicAdd(&h[d.z >> 8], 1);
            atomicAdd(&h[d.w >> 8], 1);
        }
        __syncthreads();
        for (int i = tid; i < NB; i += 256) hist_g[i * NBLK + blk] = h[i];
    } else {
        int node0 = (blk - NBLK) * 64;
        gemm_body<IN_DIM, float, false>(x, W1, nullptr, h1, N_NODES, node0, smem, smem + 64 * 68);
    }
}

// K2: fused scan+bin. Each block loads hist_g (12544 ints) into LDS, exclusive-scans it
// locally (replicated across blocks on idle CUs), takes its own cursor column, and bins
// edges bucket-major, packed 4B: src(16b) | (dst&255)<<16. Block 0 also emits bucket bases.
__global__ __launch_bounds__(256) void k2_binscan(const int* __restrict__ hist_g,
                                                  const int* __restrict__ src, const int* __restrict__ dst,
                                                  int* __restrict__ binned, int* __restrict__ bstart,
                                                  int* __restrict__ offs) {
    __shared__ int ld[NB * NBLK];   // 12544 ints = 50176 B
    __shared__ int cur[NB];
    __shared__ int wsum[4];
    int tid = threadIdx.x, blk = blockIdx.x;
    for (int i = tid; i < NB * NBLK; i += 256) ld[i] = hist_g[i];
    __syncthreads();
    const int CH = (NB * NBLK) / 256;   // 49
    int base = tid * CH;
    int s = 0;
    for (int k = 0; k < CH; k++) { int v = ld[base + k]; ld[base + k] = s; s += v; }
    int lane = tid & 63, wid = tid >> 6;
    int inc = s;
    #pragma unroll
    for (int d = 1; d < 64; d <<= 1) { int t = __shfl_up(inc, d, 64); if (lane >= d) inc += t; }
    if (lane == 63) wsum[wid] = inc;
    __syncthreads();
    if (tid == 0) {
        int a = 0;
        for (int w = 0; w < 4; w++) { int t = wsum[w]; wsum[w] = a; a += t; }
    }
    __syncthreads();
    int off = wsum[wid] + inc - s;
    for (int k = 0; k < CH; k++) ld[base + k] += off;
    __syncthreads();
    for (int b = tid; b < NB; b += 256) cur[b] = ld[b * NBLK + blk];
    if (blk == 0) {
        for (int b = tid; b < NB; b += 256) bstart[b] = ld[b * NBLK];
        if (tid == 0) { bstart[NB] = N_EDGES; offs[N_NODES] = N_EDGES; }
    }
    __syncthreads();
    const int NI = N_EDGES / 4;
    for (int i = blk * 256 + tid; i < NI; i += NBLK * 256) {
        int4 sv = ((const int4*)src)[i];
        int4 dv = ((const int4*)dst)[i];
        int p0 = atomicAdd(&cur[dv.x >> 8], 1); binned[p0] = (sv.x & 0xFFFF) | ((dv.x & 255) << 16);
        int p1 = atomicAdd(&cur[dv.y >> 8], 1); binned[p1] = (sv.y & 0xFFFF) | ((dv.y & 255) << 16);
        int p2 = atomicAdd(&cur[dv.z >> 8], 1); binned[p2] = (sv.z & 0xFFFF) | ((dv.z & 255) << 16);
        int p3 = atomicAdd(&cur[dv.w >> 8], 1); binned[p3] = (sv.w & 0xFFFF) | ((dv.w & 255) << 16);
    }
}

// K3: one block per bucket — LDS counting sort by local id; writes offs, dinv, csr_src (u16).
__global__ __launch_bounds__(256) void build_kernel(const int* __restrict__ binned, const int* __restrict__ bstart,
                                                    int* __restrict__ offs, float* __restrict__ dinv,
                                                    unsigned short* __restrict__ csr_src) {
    __shared__ int cnt[256];
    __shared__ int excl[256];
    __shared__ int rnk[256];
    __shared__ int wtot[4];
    int b = blockIdx.x, tid = threadIdx.x;
    int base = bstart[b];
    int end  = bstart[b + 1];
    cnt[tid] = 0; rnk[tid] = 0;
    __syncthreads();
    for (int j = base + tid; j < end; j += 256) atomicAdd(&cnt[(binned[j] >> 16) & 255], 1);
    __syncthreads();
    int v = cnt[tid];
    int lane = tid & 63, wid = tid >> 6;
    int inc = v;
    #pragma unroll
    for (int d = 1; d < 64; d <<= 1) { int t = __shfl_up(inc, d, 64); if (lane >= d) inc += t; }
    if (lane == 63) wtot[wid] = inc;
    __syncthreads();
    if (tid == 0) {
        int a = 0;
        for (int w = 0; w < 4; w++) { int t = wtot[w]; wtot[w] = a; a += t; }
    }
    __syncthreads();
    excl[tid] = wtot[wid] + inc - v;
    int node = b * 256 + tid;
    if (node < N_NODES) {
        offs[node] = base + excl[tid];
        dinv[node] = rsqrtf((float)v + 1.0f);
    }
    __syncthreads();
    for (int j = base + tid; j < end; j += 256) {
        int e = binned[j];
        int l = (e >> 16) & 255;
        int r = atomicAdd(&rnk[l], 1);
        csr_src[base + excl[l] + r] = (unsigned short)(e & 0xFFFF);
    }
}

// K4: out[n,c] = relu( dinv[n]*Sum_{e:dst=n} h1[src,c]*dinv[src] + dinv[n]^2*h1[n,c] + b[c] )
// h1 is UNSCALED; dinv[src] applied at gather. Wave = 1 node; 8 groups x 8 lanes;
// group g walks j=beg+g step 8, 16B row loads. [unroll 2 — round-14: unroll 4 was +6us;
// avg degree 16 / 8 groups = ~2 iters, deeper unroll has nothing to overlap]
__global__ __launch_bounds__(256) void agg1_kernel(const __half* __restrict__ hd, const int* __restrict__ offs,
                                                   const unsigned short* __restrict__ csr_src,
                                                   const float* __restrict__ dinv, const float* __restrict__ bias,
                                                   __half* __restrict__ out) {
    int lane = threadIdx.x & 63;
    int node = blockIdx.x * 4 + (threadIdx.x >> 6);   // grid*4 == N_NODES exactly
    int g = lane >> 3;
    int cc = (lane & 7) * 8;
    float acc[8] = {};
    int beg = offs[node], end = offs[node + 1];
    #pragma unroll 2
    for (int j = beg + g; j < end; j += 8) {
        int s = csr_src[j];
        float dv = dinv[s];
        float hv[8];
        load_h8(&hd[(size_t)s * 64 + cc], hv);
        #pragma unroll
        for (int i = 0; i < 8; i++) acc[i] = fmaf(hv[i], dv, acc[i]);
    }
    #pragma unroll
    for (int m = 8; m <= 32; m <<= 1) {
        #pragma unroll
        for (int i = 0; i < 8; i++) acc[i] += __shfl_xor(acc[i], m, 64);
    }
    if (g == 0) {
        float di = dinv[node];
        float d2 = di * di;
        float hn[8];
        load_h8(&hd[(size_t)node * 64 + cc], hn);
        float4 bv0 = *(const float4*)&bias[cc];
        float4 bv1 = *(const float4*)&bias[cc + 4];
        float bb[8] = {bv0.x, bv0.y, bv0.z, bv0.w, bv1.x, bv1.y, bv1.z, bv1.w};
        float r[8];
        #pragma unroll
        for (int i = 0; i < 8; i++) r[i] = fmaxf(fmaf(di, acc[i], fmaf(d2, hn[i], bb[i])), 0.0f);
        store_h8(&out[(size_t)node * 64 + cc], r);
    }
}

// K5: gemm2 = (h1_act @ W2) * dinv -> fp16 (standalone wrapper over gemm_body).
// [round-13: fusing this into agg1 as a shfl-matvec REGRESSED +14us. Keep split.]
__global__ __launch_bounds__(256) void gemm2_kernel(const __half* __restrict__ A, const float* __restrict__ W,
                                                    const float* __restrict__ dinv, __half* __restrict__ out) {
    __shared__ __align__(16) float smem[2 * 64 * 68];
    gemm_body<HID, __half, true>(A, W, dinv, out, N_NODES, blockIdx.x * 64, smem, smem + 64 * 68);
}

// K6: layer-2 agg with fused Wlin dot epilogue: writes per-node scalar ndot (fp32).
// NO cross-block protocol — round-3's fused reduce cost 265us in single-address
// arrive atomics + per-block threadfence. Plain store + tiny graphred is cheaper.
__global__ __launch_bounds__(256) void agg2dot_kernel(const __half* __restrict__ hd, const int* __restrict__ offs,
                                                      const unsigned short* __restrict__ csr_src,
                                                      const float* __restrict__ dinv, const float* __restrict__ bias,
                                                      const float* __restrict__ Wlin,
                                                      float* __restrict__ ndot) {
    int lane = threadIdx.x & 63;
    int node = blockIdx.x * 4 + (threadIdx.x >> 6);   // grid*4 == N_NODES exactly
    int g = lane >> 3;
    int cc = (lane & 7) * 8;
    float acc[8] = {};
    int beg = offs[node], end = offs[node + 1];
    #pragma unroll 2
    for (int j = beg + g; j < end; j += 8) {
        int s = csr_src[j];
        float hv[8];
        load_h8(&hd[(size_t)s * 64 + cc], hv);
        #pragma unroll
        for (int i = 0; i < 8; i++) acc[i] += hv[i];
    }
    #pragma unroll
    for (int m = 8; m <= 32; m <<= 1) {
        #pragma unroll
        for (int i = 0; i < 8; i++) acc[i] += __shfl_xor(acc[i], m, 64);
    }
    if (g == 0) {
        float di = dinv[node];
        float hn[8];
        load_h8(&hd[(size_t)node * 64 + cc], hn);
        float4 bv0 = *(const float4*)&bias[cc];
        float4 bv1 = *(const float4*)&bias[cc + 4];
        float bb[8] = {bv0.x, bv0.y, bv0.z, bv0.w, bv1.x, bv1.y, bv1.z, bv1.w};
        float4 wl0 = *(const float4*)&Wlin[cc];
        float4 wl1 = *(const float4*)&Wlin[cc + 4];
        float ww[8] = {wl0.x, wl0.y, wl0.z, wl0.w, wl1.x, wl1.y, wl1.z, wl1.w};
        float d = 0.0f;
        #pragma unroll
        for (int i = 0; i < 8; i++) {
            float rr = fmaxf(fmaf(di, acc[i] + hn[i], bb[i]), 0.0f);
            d = fmaf(rr, ww[i], d);
        }
        #pragma unroll
        for (int m = 1; m < 8; m <<= 1) d += __shfl_xor(d, m, 64);
        if ((lane & 7) == 0) ndot[node] = d;
    }
}

// K7: batch is SORTED: block g binary-searches its node range and mean-reduces
// ndot into out[g]. One dispatch, no partials, no global atomics.
__global__ __launch_bounds__(256) void graphred_kernel(const float* __restrict__ ndot, const int* __restrict__ batch,
                                                       const float* __restrict__ blin, float* __restrict__ out) {
    __shared__ float wpart[4];
    int g = blockIdx.x;
    int tid = threadIdx.x;
    int lo = 0, hi = N_NODES;
    while (lo < hi) { int m = (lo + hi) >> 1; if (batch[m] < g) lo = m + 1; else hi = m; }
    int lo2 = lo, hi2 = N_NODES;
    while (lo2 < hi2) { int m = (lo2 + hi2) >> 1; if (batch[m] < g + 1) lo2 = m + 1; else hi2 = m; }
    float s = 0.0f;
    for (int i = lo + tid; i < lo2; i += 256) s += ndot[i];
    int lane = tid & 63, wid = tid >> 6;
    #pragma unroll
    for (int m = 32; m > 0; m >>= 1) s += __shfl_down(s, m, 64);
    if (lane == 0) wpart[wid] = s;
    __syncthreads();
    if (tid == 0) {
        float t = wpart[0] + wpart[1] + wpart[2] + wpart[3];
        float cnt = (float)(lo2 - lo);
        out[g] = t / fmaxf(cnt, 1.0f) + blin[0];
    }
}

extern "C" void kernel_launch(void* const* d_in, const int* in_sizes, int n_in,
                              void* d_out, int out_size, void* d_ws, size_t ws_size,
                              hipStream_t stream) {
    const float* x    = (const float*)d_in[0];
    const int*   ei   = (const int*)d_in[1];
    const int*   batch= (const int*)d_in[2];
    const float* W1   = (const float*)d_in[3];
    const float* b1   = (const float*)d_in[4];
    const float* W2   = (const float*)d_in[5];
    const float* b2   = (const float*)d_in[6];
    const float* Wlin = (const float*)d_in[7];
    const float* blin = (const float*)d_in[8];
    float* out = (float*)d_out;
    const int* srcA = ei;
    const int* dstA = ei + N_EDGES;

    char* p = (char*)d_ws;
    auto alloc = [&](size_t n) { char* r = p; p += (n + 255) & ~(size_t)255; return r; };
    int*    hist_g  = (int*)alloc((size_t)NB * NBLK * 4);
    int*    bstart  = (int*)alloc((size_t)(NB + 1) * 4);
    int*    offs    = (int*)alloc((size_t)(N_NODES + 1) * 4);
    int*    binned  = (int*)alloc((size_t)N_EDGES * 4);
    unsigned short* csr_src = (unsigned short*)alloc((size_t)N_EDGES * 2);
    float*  dinv    = (float*)alloc((size_t)N_NODES * 4);
    float*  ndot    = (float*)alloc((size_t)N_NODES * 4);
    __half* bufA    = (__half*)alloc((size_t)N_NODES * 64 * 2);
    __half* bufB    = (__half*)alloc((size_t)N_NODES * 64 * 2);
    // no memset needed: every buffer is fully written before read

    const int GEMM1_BLOCKS = (N_NODES + 63) / 64;               // 782
    k1_kernel<<<NBLK + GEMM1_BLOCKS, 256, 0, stream>>>(dstA, hist_g, x, W1, bufA);
    k2_binscan<<<NBLK, 256, 0, stream>>>(hist_g, srcA, dstA, binned, bstart, offs);
    build_kernel<<<NB, 256, 0, stream>>>(binned, bstart, offs, dinv, csr_src);
    agg1_kernel<<<N_NODES / 4, 256, 0, stream>>>(bufA, offs, csr_src, dinv, b1, bufB);
    gemm2_kernel<<<GEMM1_BLOCKS, 256, 0, stream>>>(bufB, W2, dinv, bufA);
    agg2dot_kernel<<<N_NODES / 4, 256, 0, stream>>>(bufA, offs, csr_src, dinv, b2, Wlin, ndot);
    graphred_kernel<<<NUM_GRAPHS, 256, 0, stream>>>(ndot, batch, blin, out);
}